// Round 5
// baseline (251.485 us; speedup 1.0000x reference)
//
#include <hip/hip_runtime.h>

#define T   512
#define B   512
#define NT  64
#define QS  16            // steps per staging quarter
#define NQ  (T / QS)      // 32 quarters
#define RING 8            // LDS ring of 8 quarters (2 chunks), lead distance 3

typedef _Float16 h2 __attribute__((ext_vector_type(2)));

__device__ __forceinline__ float rflf(float x) {
    return __uint_as_float(__builtin_amdgcn_readfirstlane(__float_as_uint(x)));
}

__device__ __forceinline__ float dot2(h2 a, h2 b, float c) {
#if __has_builtin(__builtin_amdgcn_fdot2)
    return __builtin_amdgcn_fdot2(a, b, c, false);
#else
    return c + (float)a.x * (float)b.x + (float)a.y * (float)b.y;
#endif
}

// ---------------------------------------------------------------------------
// Fused CRF. Grid = 256 denom blocks (2 chains each) + 512 numerator blocks.
//
// Denominator (lane j = tag j), state per chain: q_j (f16 in LDS for the
// broadcast, fp32 in reg), integer K with score_j = S0 + K*ln2 + log q_j.
// Per step (EXACT algebra):
//   p_j  = sum_i q_i * E[i][j]        E = exp(trans) as f16 pairs, v_dot2_f32_f16
//   k    = floor(log2(p_lane0))       (exponent bits of readfirstlane -> SALU)
//   q'_j = p_j * 2^-k * X_tj          X = exp(emission), PRE-COMPUTED at staging
//   K   += k                          (masked steps: q'=q, K+=0)
// No exp/log/rcp and no global memory on the serial chain. Emissions are
// staged as f16 (XA,XB) pairs through an 8-quarter LDS ring, loaded 3-4
// quarters (48-64 steps) ahead via 8 float4 regs (no spill). Mask -> per-64-
// step ballot held in SGPRs. Two chains interleave to fill DS-latency bubbles.
// ---------------------------------------------------------------------------
__global__ __launch_bounds__(64) void crf_fused(
    const float* __restrict__ emissions,  // [T, B, NT]
    const int*   __restrict__ tags,       // [T, B]
    const int*   __restrict__ mask,       // [T, B]
    const float* __restrict__ startT,     // [NT]
    const float* __restrict__ endT,       // [NT]
    const float* __restrict__ trans,      // [NT, NT]
    float* __restrict__ out)
{
    const int j = threadIdx.x;

    __shared__ __align__(16) h2       ebuf[RING][QS][NT];  // (XA,XB) pairs, 32 KB
    __shared__ __align__(16) _Float16 qsA[NT];
    __shared__ __align__(16) _Float16 qsB[NT];

    if (blockIdx.x < 256) {
        // =============== denominator, chains b0, b1 ========================
        const int b0 = 2 * blockIdx.x;
        const int b1 = b0 + 1;

        // E = exp(trans), column j, as f16 pairs over i (32 VGPRs)
        h2 Eh[NT / 2];
#pragma unroll
        for (int m = 0; m < NT / 2; ++m) {
            Eh[m].x = (_Float16)__expf(trans[(2 * m)     * NT + j]);
            Eh[m].y = (_Float16)__expf(trans[(2 * m + 1) * NT + j]);
        }

        // staging mapping: lane j covers rows 4k + (j>>4) of a quarter,
        // cols (j&15)*4 .. +3   (coalesced 1 KB per float4 load instr)
        const int jr = j >> 4;
        const int c0 = (j & 15) * 4;
        float4 sA[4], sB[4];

        auto issue_q = [&](int g) {
#pragma unroll
            for (int k = 0; k < 4; ++k) {
                const int t = g * QS + 4 * k + jr;
                sA[k] = *(const float4*)&emissions[((size_t)t * B + b0) * NT + c0];
                sB[k] = *(const float4*)&emissions[((size_t)t * B + b1) * NT + c0];
            }
        };
        auto write_q = [&](int g) {
#pragma unroll
            for (int k = 0; k < 4; ++k) {
                h2 w0, w1, w2, w3;
                w0.x = (_Float16)__expf(sA[k].x); w0.y = (_Float16)__expf(sB[k].x);
                w1.x = (_Float16)__expf(sA[k].y); w1.y = (_Float16)__expf(sB[k].y);
                w2.x = (_Float16)__expf(sA[k].z); w2.y = (_Float16)__expf(sB[k].z);
                w3.x = (_Float16)__expf(sA[k].w); w3.y = (_Float16)__expf(sB[k].w);
                h2* dst = &ebuf[g & (RING - 1)][4 * k + jr][c0];
                dst[0] = w0; dst[1] = w1; dst[2] = w2; dst[3] = w3;
            }
        };

        // prologue: quarters 0..2 staged now; quarter 3 left in regs
        for (int g = 0; g < 3; ++g) { issue_q(g); write_q(g); }
        issue_q(3);

        // t = 0 init
        const float e0A = emissions[(size_t)b0 * NT + j];
        const float e0B = emissions[(size_t)b1 * NT + j];
        const float sc0A = startT[j] + e0A;
        const float sc0B = startT[j] + e0B;
        const float S0A = rflf(sc0A);
        const float S0B = rflf(sc0B);
        float qA = __expf(sc0A - S0A);
        float qB = __expf(sc0B - S0B);
        qsA[j] = (_Float16)qA;
        qsB[j] = (_Float16)qB;
        int KA = 0, KB = 0;

        // mask pipeline: per-lane values for chunk 0 (64 steps per chunk)
        int mpreA = mask[j * B + b0];
        int mpreB = mask[j * B + b1];
        unsigned long long mbcA = 0, mbcB = 0;

        for (int x = 0; x < NQ; ++x) {
            // quarter boundary: commit quarter min(x+3,31), refill with x+4
            const int gw = (x + 3 < NQ) ? x + 3 : NQ - 1;
            write_q(gw);
            const int gl = (x + 4 < NQ) ? x + 4 : NQ - 1;
            issue_q(gl);

            if ((x & 3) == 0) {   // chunk boundary: ballot mask, prefetch next
                mbcA = __ballot(mpreA != 0);
                mbcB = __ballot(mpreB != 0);
                const int cn = ((x >> 2) + 1 < 8) ? (x >> 2) + 1 : 7;
                mpreA = mask[(cn * 64 + j) * B + b0];
                mpreB = mask[(cn * 64 + j) * B + b1];
            }

            const int tt0 = (x == 0) ? 1 : 0;
#pragma unroll 4
            for (int tt = tt0; tt < QS; ++tt) {
                const int ttc = ((x & 3) << 4) + tt;
                const h2 X2 = ebuf[x & (RING - 1)][tt][j];

                // chain A matvec (8x ds_read_b128 broadcast + 32 dot2)
                const uint4* qa4 = (const uint4*)qsA;
                float aA0 = 0.f, aA1 = 0.f, aA2 = 0.f, aA3 = 0.f;
#pragma unroll
                for (int m = 0; m < 8; m += 2) {
                    const uint4 u = qa4[m];
                    const uint4 v = qa4[m + 1];
                    aA0 = dot2(__builtin_bit_cast(h2, u.x), Eh[4 * m + 0], aA0);
                    aA1 = dot2(__builtin_bit_cast(h2, u.y), Eh[4 * m + 1], aA1);
                    aA2 = dot2(__builtin_bit_cast(h2, u.z), Eh[4 * m + 2], aA2);
                    aA3 = dot2(__builtin_bit_cast(h2, u.w), Eh[4 * m + 3], aA3);
                    aA0 = dot2(__builtin_bit_cast(h2, v.x), Eh[4 * m + 4], aA0);
                    aA1 = dot2(__builtin_bit_cast(h2, v.y), Eh[4 * m + 5], aA1);
                    aA2 = dot2(__builtin_bit_cast(h2, v.z), Eh[4 * m + 6], aA2);
                    aA3 = dot2(__builtin_bit_cast(h2, v.w), Eh[4 * m + 7], aA3);
                }
                const float pA = (aA0 + aA1) + (aA2 + aA3);

                // chain B matvec
                const uint4* qb4 = (const uint4*)qsB;
                float aB0 = 0.f, aB1 = 0.f, aB2 = 0.f, aB3 = 0.f;
#pragma unroll
                for (int m = 0; m < 8; m += 2) {
                    const uint4 u = qb4[m];
                    const uint4 v = qb4[m + 1];
                    aB0 = dot2(__builtin_bit_cast(h2, u.x), Eh[4 * m + 0], aB0);
                    aB1 = dot2(__builtin_bit_cast(h2, u.y), Eh[4 * m + 1], aB1);
                    aB2 = dot2(__builtin_bit_cast(h2, u.z), Eh[4 * m + 2], aB2);
                    aB3 = dot2(__builtin_bit_cast(h2, u.w), Eh[4 * m + 3], aB3);
                    aB0 = dot2(__builtin_bit_cast(h2, v.x), Eh[4 * m + 4], aB0);
                    aB1 = dot2(__builtin_bit_cast(h2, v.y), Eh[4 * m + 5], aB1);
                    aB2 = dot2(__builtin_bit_cast(h2, v.z), Eh[4 * m + 6], aB2);
                    aB3 = dot2(__builtin_bit_cast(h2, v.w), Eh[4 * m + 7], aB3);
                }
                const float pB = (aB0 + aB1) + (aB2 + aB3);

                // power-of-2 renormalization: k from lane-0 exponent (SALU)
                const int bitsA = __builtin_amdgcn_readfirstlane(__float_as_int(pA));
                const int bitsB = __builtin_amdgcn_readfirstlane(__float_as_int(pB));
                const int kA = ((bitsA >> 23) & 255) - 127;
                const int kB = ((bitsB >> 23) & 255) - 127;
                const float rA = __int_as_float((127 - kA) << 23);
                const float rB = __int_as_float((127 - kB) << 23);

                const bool mA = (mbcA >> ttc) & 1ull;
                const bool mB = (mbcB >> ttc) & 1ull;
                const float qnA = pA * rA * (float)X2.x;
                const float qnB = pB * rB * (float)X2.y;
                qA = mA ? qnA : qA;
                qB = mB ? qnB : qB;
                KA += mA ? kA : 0;
                KB += mB ? kB : 0;
                qsA[j] = (_Float16)qA;
                qsB[j] = (_Float16)qB;
            }
        }

        // den_b = S0 + K*ln2 + log( sum_j q_j * exp(endT_j) )
        const float eT = __expf(endT[j]);
        float vA = qA * eT;
        float vB = qB * eT;
#pragma unroll
        for (int off = 32; off > 0; off >>= 1) {
            vA += __shfl_xor(vA, off);
            vB += __shfl_xor(vB, off);
        }
        if (j == 0) {
            const float denA = S0A + (float)KA * 0.69314718f + __logf(vA);
            const float denB = S0B + (float)KB * 0.69314718f + __logf(vB);
            atomicAdd(out, -(denA + denB));   // llh = num - den
        }

    } else {
        // =============== numerator wave, b = blockIdx.x - 256 ===============
        const int b = blockIdx.x - 256;

        float acc = 0.f;
        int   cnt = 0;
#pragma unroll
        for (int m = 0; m < T / 64; ++m) {
            const int t  = j + 64 * m;
            const int mv = mask[t * B + b];
            const int tg = tags[t * B + b];
            cnt += (int)__popcll(__ballot(mv != 0));
            if (t == 0) {
                acc += startT[tg] + emissions[(size_t)b * NT + tg];
            } else if (mv) {
                const int tp = tags[(t - 1) * B + b];
                acc += trans[tp * NT + tg]
                     + emissions[(size_t)(t * B + b) * NT + tg];
            }
        }
#pragma unroll
        for (int off = 32; off > 0; off >>= 1)
            acc += __shfl_xor(acc, off);
        if (j == 0) {
            const int last = tags[(size_t)(cnt - 1) * B + b];
            atomicAdd(out, acc + endT[last]);
        }
    }
}

extern "C" void kernel_launch(void* const* d_in, const int* in_sizes, int n_in,
                              void* d_out, int out_size, void* d_ws, size_t ws_size,
                              hipStream_t stream) {
    const float* emissions = (const float*)d_in[0];
    const int*   tags      = (const int*)  d_in[1];
    const int*   mask      = (const int*)  d_in[2];
    const float* startT    = (const float*)d_in[3];
    const float* endT      = (const float*)d_in[4];
    const float* trans     = (const float*)d_in[5];
    float* out = (float*)d_out;

    hipMemsetAsync(out, 0, sizeof(float), stream);
    crf_fused<<<256 + B, 64, 0, stream>>>(
        emissions, tags, mask, startT, endT, trans, out);
}

// Round 6
// 194.566 us; speedup vs baseline: 1.2925x; 1.2925x over previous
//
#include <hip/hip_runtime.h>

#define T   512
#define B   512
#define NT  64
#define QS  16            // steps per staging quarter
#define NQ  (T / QS)      // 32 quarters
#define RING 4            // LDS ring: 4 quarters (64 steps), lead distance 3

typedef _Float16 h2 __attribute__((ext_vector_type(2)));

__device__ __forceinline__ float rflf(float x) {
    return __uint_as_float(__builtin_amdgcn_readfirstlane(__float_as_uint(x)));
}

__device__ __forceinline__ float dot2(h2 a, h2 b, float c) {
#if __has_builtin(__builtin_amdgcn_fdot2)
    return __builtin_amdgcn_fdot2(a, b, c, false);
#else
    return c + (float)a.x * (float)b.x + (float)a.y * (float)b.y;
#endif
}

// ---------------------------------------------------------------------------
// Fused CRF. Grid = 512 denom blocks (1 chain each, single wave) + 512
// numerator blocks.
//
// Denominator (lane j = tag j). Wall time = 511 * L_step (latency-bound, all
// waves concurrent), so this round minimizes single-wave L by REMOVING the
// per-step LDS round-trip for the q broadcast:
//   - q' packed to f16 pairs in even lanes (1 DPP quad-perm + cvt_pkrtz),
//   - 32x v_readlane -> SGPRs (SALU pipe, ~1cy, no lgkm),
//   - 32x v_dot2_f32_f16 with SGPR src0 against E-column regs.
// Renormalization is power-of-2 from lane-0 exponent bits (SALU), score
// tracked as S0 + K*ln2 + log q. X = exp(emission) pre-computed at staging
// time into a 4-quarter LDS ring loaded ~3 quarters (48 steps) ahead; the
// only in-loop DS op is one conflict-free ds_read_b32. No exp/log/rcp and
// no global/LDS-write on the serial chain.
// ---------------------------------------------------------------------------
__global__ __launch_bounds__(64) void crf_fused(
    const float* __restrict__ emissions,  // [T, B, NT]
    const int*   __restrict__ tags,       // [T, B]
    const int*   __restrict__ mask,       // [T, B]
    const float* __restrict__ startT,     // [NT]
    const float* __restrict__ endT,       // [NT]
    const float* __restrict__ trans,      // [NT, NT]
    float* __restrict__ out)
{
    const int j = threadIdx.x;

    __shared__ __align__(16) float ebuf[RING][QS][NT];   // X = exp(e), 16 KB

    if (blockIdx.x < B) {
        // =============== denominator chain, b = blockIdx.x ==================
        const int b = blockIdx.x;

        // E = exp(trans) column j as f16 pairs over i (32 VGPRs)
        h2 Eh[NT / 2];
#pragma unroll
        for (int m = 0; m < NT / 2; ++m) {
            Eh[m].x = (_Float16)__expf(trans[(2 * m)     * NT + j]);
            Eh[m].y = (_Float16)__expf(trans[(2 * m + 1) * NT + j]);
        }

        // staging: lane j covers step 4k + (j>>4) of a quarter, cols (j&15)*4
        const int jr = j >> 4;
        const int c0 = (j & 15) * 4;
        float4 sA[4];

        auto issue_q = [&](int g) {
#pragma unroll
            for (int k = 0; k < 4; ++k) {
                const int t = g * QS + 4 * k + jr;
                sA[k] = *(const float4*)&emissions[((size_t)t * B + b) * NT + c0];
            }
        };
        auto write_q = [&](int g) {   // exp() applied here, off the chain
#pragma unroll
            for (int k = 0; k < 4; ++k) {
                float4 w;
                w.x = __expf(sA[k].x); w.y = __expf(sA[k].y);
                w.z = __expf(sA[k].z); w.w = __expf(sA[k].w);
                *(float4*)&ebuf[g & (RING - 1)][4 * k + jr][c0] = w;
            }
        };

        for (int g = 0; g < 3; ++g) { issue_q(g); write_q(g); }
        issue_q(3);

        // t = 0 init
        const float e0  = emissions[(size_t)b * NT + j];
        const float sc0 = startT[j] + e0;
        const float S0  = rflf(sc0);
        float q = __expf(sc0 - S0);
        int   K = 0;

        // initial f16 pair pack (even lane 2n holds (q_2n, q_2n+1))
        int pk_i;
        {
            const int qi = __float_as_int(q);
            const int qo = __builtin_amdgcn_update_dpp(0, qi, 0xB1, 0xF, 0xF, true);
            pk_i = __builtin_bit_cast(int,
                    __builtin_amdgcn_cvt_pkrtz(q, __int_as_float(qo)));
        }

        int mpre = mask[j * B + b];            // chunk-0 mask column
        unsigned long long mbc = 0;

        for (int x = 0; x < NQ; ++x) {
            const int gw = (x + 3 < NQ) ? x + 3 : NQ - 1;
            write_q(gw);
            const int gl = (x + 4 < NQ) ? x + 4 : NQ - 1;
            issue_q(gl);

            if ((x & 3) == 0) {                // 64-step chunk boundary
                mbc = __ballot(mpre != 0);
                const int cn = ((x >> 2) + 1 < 8) ? (x >> 2) + 1 : 7;
                mpre = mask[(cn * 64 + j) * B + b];
            }

            const int tt0 = (x == 0) ? 1 : 0;
#pragma unroll 4
            for (int tt = tt0; tt < QS; ++tt) {
                const float X = ebuf[x & (RING - 1)][tt][j];  // only DS op

                // matvec: p_j = sum_i q_i E[i][j]; q pairs via SALU readlane
                float a0 = 0.f, a1 = 0.f, a2 = 0.f, a3 = 0.f;
#pragma unroll
                for (int n = 0; n < 8; ++n) {
                    const int u0 = __builtin_amdgcn_readlane(pk_i, 8 * n + 0);
                    const int u1 = __builtin_amdgcn_readlane(pk_i, 8 * n + 2);
                    const int u2 = __builtin_amdgcn_readlane(pk_i, 8 * n + 4);
                    const int u3 = __builtin_amdgcn_readlane(pk_i, 8 * n + 6);
                    a0 = dot2(__builtin_bit_cast(h2, u0), Eh[4 * n + 0], a0);
                    a1 = dot2(__builtin_bit_cast(h2, u1), Eh[4 * n + 1], a1);
                    a2 = dot2(__builtin_bit_cast(h2, u2), Eh[4 * n + 2], a2);
                    a3 = dot2(__builtin_bit_cast(h2, u3), Eh[4 * n + 3], a3);
                }
                const float p = (a0 + a1) + (a2 + a3);

                // power-of-2 renorm from lane-0 exponent (SALU side)
                const int bits = __builtin_amdgcn_readfirstlane(__float_as_int(p));
                const int k    = ((bits >> 23) & 255) - 127;
                const float r  = __int_as_float((127 - k) << 23);

                const int  ttc = ((x & 3) << 4) + tt;
                const bool mc  = (mbc >> ttc) & 1ull;
                const float qn = p * r * X;
                q = mc ? qn : q;
                K += mc ? k : 0;

                // repack f16 pair for next step's readlanes
                const int qi = __float_as_int(q);
                const int qo = __builtin_amdgcn_update_dpp(0, qi, 0xB1, 0xF, 0xF, true);
                pk_i = __builtin_bit_cast(int,
                        __builtin_amdgcn_cvt_pkrtz(q, __int_as_float(qo)));
            }
        }

        // den_b = S0 + K*ln2 + log( sum_j q_j * exp(endT_j) )
        float v = q * __expf(endT[j]);
#pragma unroll
        for (int off = 32; off > 0; off >>= 1)
            v += __shfl_xor(v, off);
        if (j == 0)
            atomicAdd(out, -(S0 + (float)K * 0.69314718f + __logf(v)));

    } else {
        // =============== numerator wave, b = blockIdx.x - B =================
        const int b = blockIdx.x - B;

        float acc = 0.f;
        int   cnt = 0;
#pragma unroll
        for (int m = 0; m < T / 64; ++m) {
            const int t  = j + 64 * m;
            const int mv = mask[t * B + b];
            const int tg = tags[t * B + b];
            cnt += (int)__popcll(__ballot(mv != 0));
            if (t == 0) {
                acc += startT[tg] + emissions[(size_t)b * NT + tg];
            } else if (mv) {
                const int tp = tags[(t - 1) * B + b];
                acc += trans[tp * NT + tg]
                     + emissions[(size_t)(t * B + b) * NT + tg];
            }
        }
#pragma unroll
        for (int off = 32; off > 0; off >>= 1)
            acc += __shfl_xor(acc, off);
        if (j == 0) {
            const int last = tags[(size_t)(cnt - 1) * B + b];
            atomicAdd(out, acc + endT[last]);
        }
    }
}

extern "C" void kernel_launch(void* const* d_in, const int* in_sizes, int n_in,
                              void* d_out, int out_size, void* d_ws, size_t ws_size,
                              hipStream_t stream) {
    const float* emissions = (const float*)d_in[0];
    const int*   tags      = (const int*)  d_in[1];
    const int*   mask      = (const int*)  d_in[2];
    const float* startT    = (const float*)d_in[3];
    const float* endT      = (const float*)d_in[4];
    const float* trans     = (const float*)d_in[5];
    float* out = (float*)d_out;

    hipMemsetAsync(out, 0, sizeof(float), stream);
    crf_fused<<<2 * B, 64, 0, stream>>>(
        emissions, tags, mask, startT, endT, trans, out);
}